// Round 2
// baseline (895.966 us; speedup 1.0000x reference)
//
#include <hip/hip_runtime.h>

// Problem constants (from reference): B=2, S=2048, E=2048, H=16, D=128.
#define BATCH 2
#define SEQ   2048
#define EMB   2048
#define NH    16
#define HD    128

typedef unsigned short u16;
typedef u16 u16x8 __attribute__((ext_vector_type(8)));
typedef __bf16 bf16x8 __attribute__((ext_vector_type(8)));
typedef float f32x4 __attribute__((ext_vector_type(4)));

__device__ __forceinline__ u16 f2bf(float f) {
  union { float f; unsigned u; } v; v.f = f;
  unsigned r = v.u + 0x7FFFu + ((v.u >> 16) & 1u);
  return (u16)(r >> 16);
}
__device__ __forceinline__ float bf2f(u16 b) {
  union { unsigned u; float f; } v; v.u = ((unsigned)b) << 16;
  return v.f;
}
__device__ __forceinline__ void gload_lds16(const u16* g, u16* l) {
  __builtin_amdgcn_global_load_lds(
      (__attribute__((address_space(1))) void*)(void*)g,
      (__attribute__((address_space(3))) void*)(void*)l, 16, 0, 0);
}

// ---------------- f32 -> bf16 conversion (vectorized, grid-stride) ----------
__global__ void cvt_f32_bf16(const float* __restrict__ in, u16* __restrict__ out, int n) {
  int i = (blockIdx.x * 256 + threadIdx.x) * 4;
  const int stride = gridDim.x * 256 * 4;
  for (; i + 3 < n; i += stride) {
    float4 v = *(const float4*)(in + i);
    u16 o0 = f2bf(v.x), o1 = f2bf(v.y), o2 = f2bf(v.z), o3 = f2bf(v.w);
    unsigned lo = (unsigned)o0 | ((unsigned)o1 << 16);
    unsigned hi = (unsigned)o2 | ((unsigned)o3 << 16);
    uint2 pack; pack.x = lo; pack.y = hi;
    *(uint2*)(out + i) = pack;
  }
}

// ---------------- RoPE cos/sin table ----------------------------------------
__global__ void rope_table(float* __restrict__ cosT, float* __restrict__ sinT) {
  const int s = blockIdx.x;      // 0..S-1
  const int j = threadIdx.x;     // 0..63
  float inv = powf(10000.0f, -(float)j / 64.0f);
  float ang = (float)s * inv;
  cosT[s * 64 + j] = cosf(ang);
  sinT[s * 64 + j] = sinf(ang);
}

// ---------------- RoPE apply (in-place, (b,h,s,d) bf16 layout) --------------
__global__ void rope_apply(u16* __restrict__ q, const float* __restrict__ cosT,
                           const float* __restrict__ sinT) {
  const int idx = blockIdx.x * 256 + threadIdx.x; // B*H*S*64 threads
  const int j = idx & 63;
  const int s = (idx >> 6) & (SEQ - 1);
  const int bh = idx >> 17;
  u16* base = q + ((long)bh * SEQ + s) * HD;
  float x1 = bf2f(base[j]), x2 = bf2f(base[j + 64]);
  float c = cosT[s * 64 + j], sn = sinT[s * 64 + j];
  base[j]      = f2bf(x1 * c - x2 * sn);
  base[j + 64] = f2bf(x1 * sn + x2 * c);
}

// ---------------- GEMM: out = A(MxK) * Bw(NxK)^T + bias ---------------------
// MODE 0: write bf16 to (b,h,s,d) layout (QKV). MODE 1: write f32 row-major.
template <int MODE>
__global__ __launch_bounds__(256)
void gemm_bt(const u16* __restrict__ A, const u16* __restrict__ Bw,
             const float* __restrict__ bias, void* __restrict__ out,
             int M, int N, int K) {
  __shared__ u16 As[128 * 32];
  __shared__ u16 Bs[128 * 32];
  const int tid = threadIdx.x;
  const int wave = tid >> 6, lane = tid & 63;
  const int lr = lane & 15, lk = lane >> 4;
  const int m0 = blockIdx.y * 128, n0 = blockIdx.x * 128;
  const int wr = (wave >> 1) * 64, wc = (wave & 1) * 64;
  f32x4 acc[4][4] = {};
  for (int kt = 0; kt < K; kt += 32) {
#pragma unroll
    for (int c = 0; c < 2; ++c) {
      int idx = c * 256 + tid;            // 16B chunk id (512 per tile)
      int row = idx >> 2, col = (idx & 3) * 8;
      gload_lds16(A + (long)(m0 + row) * K + kt + col, As + idx * 8);
      gload_lds16(Bw + (long)(n0 + row) * K + kt + col, Bs + idx * 8);
    }
    __syncthreads();
    bf16x8 af[4], bfv[4];
#pragma unroll
    for (int m = 0; m < 4; ++m)
      af[m] = *(const bf16x8*)&As[(wr + m * 16 + lr) * 32 + lk * 8];
#pragma unroll
    for (int n = 0; n < 4; ++n)
      bfv[n] = *(const bf16x8*)&Bs[(wc + n * 16 + lr) * 32 + lk * 8];
#pragma unroll
    for (int m = 0; m < 4; ++m)
#pragma unroll
      for (int n = 0; n < 4; ++n)
        acc[m][n] = __builtin_amdgcn_mfma_f32_16x16x32_bf16(af[m], bfv[n], acc[m][n], 0, 0, 0);
    __syncthreads();
  }
  // Epilogue. C/D layout: row = lk*4 + i, col = lr  [m89-verified]
#pragma unroll
  for (int n = 0; n < 4; ++n) {
    const int col = n0 + wc + n * 16 + lr;
    const float bb = bias[col];
#pragma unroll
    for (int m = 0; m < 4; ++m) {
      const int rbase = m0 + wr + m * 16 + lk * 4;
#pragma unroll
      for (int i = 0; i < 4; ++i) {
        const int row = rbase + i;
        const float val = acc[m][n][i] + bb;
        if (MODE == 0) {
          const int b = row >> 11, s = row & (SEQ - 1);
          const int h = col >> 7, d = col & (HD - 1);
          ((u16*)out)[(((long)(b * NH + h)) * SEQ + s) * HD + d] = f2bf(val);
        } else {
          ((float*)out)[(long)row * EMB + col] = val;
        }
      }
    }
  }
}

// ---------------- Flash attention (causal), Q/K/V in (b,h,s,d) bf16 ---------
// Block: (qt, bh). 4 waves x 16 q-rows = 64-row Q tile; KV tiles of 64.
__global__ __launch_bounds__(256)
void attn_fwd(const u16* __restrict__ Q, const u16* __restrict__ K,
              const u16* __restrict__ V, u16* __restrict__ O) {
  __shared__ u16 Ks[64 * 128];
  __shared__ u16 Vt[128 * 72];      // transposed V, padded stride 72
  __shared__ u16 Ps[4][16 * 64];    // per-wave P tile
  const int tid = threadIdx.x, wave = tid >> 6, lane = tid & 63;
  const int lr = lane & 15, lk = lane >> 4;
  const int bh = blockIdx.y, qt = blockIdx.x;
  const int qs = qt * 64;
  const long hoff = (long)bh * SEQ * HD;
  const u16* qb = Q + hoff + (long)(qs + wave * 16) * HD;

  bf16x8 qf[4];
#pragma unroll
  for (int ks = 0; ks < 4; ++ks)
    qf[ks] = *(const bf16x8*)(qb + (long)lr * HD + ks * 32 + lk * 8);

  f32x4 o[8] = {};
  float m_run[4] = {-1e30f, -1e30f, -1e30f, -1e30f};
  float l_run[4] = {0.f, 0.f, 0.f, 0.f};
  const float scale = 0.08838834764831845f;  // 1/sqrt(128)

  for (int t0 = 0; t0 <= qs; t0 += 64) {
    // stage K tile (64x128, linear) via async global->LDS
#pragma unroll
    for (int c = 0; c < 4; ++c) {
      int idx = c * 256 + tid;
      gload_lds16(K + hoff + (long)t0 * HD + idx * 8, Ks + idx * 8);
    }
    // stage V with transpose: Vt[d][t], stride 72, lane-staggered writes
#pragma unroll
    for (int p = 0; p < 4; ++p) {
      int r = (tid >> 4) + p * 16;
      int cg = tid & 15;
      u16x8 v8 = *(const u16x8*)(V + hoff + (long)(t0 + r) * HD + cg * 8);
#pragma unroll
      for (int j = 0; j < 8; ++j) {
        int jj = (j + ((tid >> 4) & 3) * 2) & 7;
        Vt[(cg * 8 + jj) * 72 + r] = v8[jj];
      }
    }
    __syncthreads();

    // QK^T: scores 16x64 per wave
    f32x4 sc[4] = {};
#pragma unroll
    for (int tc = 0; tc < 4; ++tc)
#pragma unroll
      for (int ks = 0; ks < 4; ++ks) {
        bf16x8 kb = *(const bf16x8*)&Ks[(tc * 16 + lr) * 128 + ks * 32 + lk * 8];
        sc[tc] = __builtin_amdgcn_mfma_f32_16x16x32_bf16(qf[ks], kb, sc[tc], 0, 0, 0);
      }

    const bool diag = (t0 == qs);
    float rmax[4] = {-1e30f, -1e30f, -1e30f, -1e30f};
#pragma unroll
    for (int tc = 0; tc < 4; ++tc)
#pragma unroll
      for (int i = 0; i < 4; ++i) {
        float v = sc[tc][i] * scale;
        if (diag) {
          int tg = t0 + tc * 16 + lr;
          int qg = qs + wave * 16 + lk * 4 + i;
          if (tg > qg) v = -1e30f;
        }
        sc[tc][i] = v;
        rmax[i] = fmaxf(rmax[i], v);
      }
#pragma unroll
    for (int off = 1; off < 16; off <<= 1)
#pragma unroll
      for (int i = 0; i < 4; ++i)
        rmax[i] = fmaxf(rmax[i], __shfl_xor(rmax[i], off, 64));

    float alpha[4], rsum[4];
#pragma unroll
    for (int i = 0; i < 4; ++i) {
      float mn = fmaxf(m_run[i], rmax[i]);
      alpha[i] = __expf(m_run[i] - mn);
      m_run[i] = mn;
      rsum[i] = 0.f;
    }
#pragma unroll
    for (int tc = 0; tc < 4; ++tc)
#pragma unroll
      for (int i = 0; i < 4; ++i) {
        float p = __expf(sc[tc][i] - m_run[i]);
        sc[tc][i] = p;
        rsum[i] += p;
      }
#pragma unroll
    for (int off = 1; off < 16; off <<= 1)
#pragma unroll
      for (int i = 0; i < 4; ++i)
        rsum[i] += __shfl_xor(rsum[i], off, 64);
#pragma unroll
    for (int i = 0; i < 4; ++i) l_run[i] = l_run[i] * alpha[i] + rsum[i];
#pragma unroll
    for (int dc = 0; dc < 8; ++dc)
#pragma unroll
      for (int i = 0; i < 4; ++i) o[dc][i] *= alpha[i];

    // P (C-layout) -> LDS -> A-layout frags
    u16* pw = Ps[wave];
#pragma unroll
    for (int tc = 0; tc < 4; ++tc)
#pragma unroll
      for (int i = 0; i < 4; ++i)
        pw[(lk * 4 + i) * 64 + tc * 16 + lr] = f2bf(sc[tc][i]);
    asm volatile("s_waitcnt lgkmcnt(0)" ::: "memory");

    // PV: o(16x128) += P(16x64) * V(64x128)
#pragma unroll
    for (int ks2 = 0; ks2 < 2; ++ks2) {
      bf16x8 pa = *(const bf16x8*)&pw[lr * 64 + ks2 * 32 + lk * 8];
#pragma unroll
      for (int dc = 0; dc < 8; ++dc) {
        bf16x8 vb = *(const bf16x8*)&Vt[(dc * 16 + lr) * 72 + ks2 * 32 + lk * 8];
        o[dc] = __builtin_amdgcn_mfma_f32_16x16x32_bf16(pa, vb, o[dc], 0, 0, 0);
      }
    }
    __syncthreads();
  }

  // epilogue: write (b,s,h*D+d) bf16
  const int b = bh >> 4, h = bh & 15;
#pragma unroll
  for (int i = 0; i < 4; ++i) {
    float inv = 1.0f / l_run[i];
    int s = qs + wave * 16 + lk * 4 + i;
    u16* orow = O + ((long)b * SEQ + s) * EMB + h * HD;
#pragma unroll
    for (int dc = 0; dc < 8; ++dc)
      orow[dc * 16 + lr] = f2bf(o[dc][i] * inv);
  }
}

// ---------------- launcher --------------------------------------------------
extern "C" void kernel_launch(void* const* d_in, const int* in_sizes, int n_in,
                              void* d_out, int out_size, void* d_ws, size_t ws_size,
                              hipStream_t stream) {
  const float* x  = (const float*)d_in[0];
  const float* wq = (const float*)d_in[1];
  const float* bq = (const float*)d_in[2];
  const float* wk = (const float*)d_in[3];
  const float* bk = (const float*)d_in[4];
  const float* wv = (const float*)d_in[5];
  const float* bv = (const float*)d_in[6];
  const float* wo = (const float*)d_in[7];
  const float* bo = (const float*)d_in[8];
  float* out = (float*)d_out;

  char* ws = (char*)d_ws;
  u16* xb  = (u16*)(ws + 0);            // 16,777,216 B
  u16* wqb = (u16*)(ws + 16777216);     //  8,388,608 B
  u16* wkb = (u16*)(ws + 25165824);
  u16* wvb = (u16*)(ws + 33554432);
  u16* wob = (u16*)(ws + 41943040);
  u16* qr  = (u16*)(ws + 50331648);     // 16,777,216 B each
  u16* kr  = (u16*)(ws + 67108864);
  u16* vr  = (u16*)(ws + 83886080);
  u16* ao  = (u16*)(ws + 100663296);
  float* cosT = (float*)(ws + 117440512);
  float* sinT = (float*)(ws + 117964800);
  // total: 118,489,088 B

  cvt_f32_bf16<<<2048, 256, 0, stream>>>(x, xb, BATCH * SEQ * EMB);
  cvt_f32_bf16<<<1024, 256, 0, stream>>>(wq, wqb, EMB * EMB);
  cvt_f32_bf16<<<1024, 256, 0, stream>>>(wk, wkb, EMB * EMB);
  cvt_f32_bf16<<<1024, 256, 0, stream>>>(wv, wvb, EMB * EMB);
  cvt_f32_bf16<<<1024, 256, 0, stream>>>(wo, wob, EMB * EMB);
  rope_table<<<SEQ, 64, 0, stream>>>(cosT, sinT);

  dim3 gg(EMB / 128, (BATCH * SEQ) / 128);
  gemm_bt<0><<<gg, 256, 0, stream>>>(xb, wqb, bq, qr, BATCH * SEQ, EMB, EMB);
  gemm_bt<0><<<gg, 256, 0, stream>>>(xb, wkb, bk, kr, BATCH * SEQ, EMB, EMB);
  gemm_bt<0><<<gg, 256, 0, stream>>>(xb, wvb, bv, vr, BATCH * SEQ, EMB, EMB);

  rope_apply<<<(BATCH * NH * SEQ * 64) / 256, 256, 0, stream>>>(qr, cosT, sinT);
  rope_apply<<<(BATCH * NH * SEQ * 64) / 256, 256, 0, stream>>>(kr, cosT, sinT);

  attn_fwd<<<dim3(SEQ / 64, BATCH * NH), 256, 0, stream>>>(qr, kr, vr, ao);

  gemm_bt<1><<<gg, 256, 0, stream>>>(ao, wob, bo, out, BATCH * SEQ, EMB, EMB);
}

// Round 4
// 601.539 us; speedup vs baseline: 1.4895x; 1.4895x over previous
//
#include <hip/hip_runtime.h>

// Problem constants (from reference): B=2, S=2048, E=2048, H=16, D=128.
#define BATCH 2
#define SEQ   2048
#define EMB   2048
#define NH    16
#define HD    128

typedef unsigned short u16;
typedef u16 u16x8 __attribute__((ext_vector_type(8)));
typedef __bf16 bf16x8 __attribute__((ext_vector_type(8)));
typedef float f32x4 __attribute__((ext_vector_type(4)));

__device__ __forceinline__ u16 f2bf(float f) {
  union { float f; unsigned u; } v; v.f = f;
  unsigned r = v.u + 0x7FFFu + ((v.u >> 16) & 1u);
  return (u16)(r >> 16);
}
__device__ __forceinline__ float bf2f(u16 b) {
  union { unsigned u; float f; } v; v.u = ((unsigned)b) << 16;
  return v.f;
}
__device__ __forceinline__ void gload_lds16(const u16* g, u16* l) {
  __builtin_amdgcn_global_load_lds(
      (__attribute__((address_space(1))) void*)(void*)g,
      (__attribute__((address_space(3))) void*)(void*)l, 16, 0, 0);
}

// ---------------- f32 -> bf16 conversion (vectorized, grid-stride) ----------
__global__ void cvt_f32_bf16(const float* __restrict__ in, u16* __restrict__ out, int n) {
  int i = (blockIdx.x * 256 + threadIdx.x) * 4;
  const int stride = gridDim.x * 256 * 4;
  for (; i + 3 < n; i += stride) {
    float4 v = *(const float4*)(in + i);
    u16 o0 = f2bf(v.x), o1 = f2bf(v.y), o2 = f2bf(v.z), o3 = f2bf(v.w);
    unsigned lo = (unsigned)o0 | ((unsigned)o1 << 16);
    unsigned hi = (unsigned)o2 | ((unsigned)o3 << 16);
    uint2 pack; pack.x = lo; pack.y = hi;
    *(uint2*)(out + i) = pack;
  }
}

// ---------------- RoPE cos/sin table ----------------------------------------
__global__ void rope_table(float* __restrict__ cosT, float* __restrict__ sinT) {
  const int s = blockIdx.x;      // 0..S-1
  const int j = threadIdx.x;     // 0..63
  float inv = powf(10000.0f, -(float)j / 64.0f);
  float ang = (float)s * inv;
  cosT[s * 64 + j] = cosf(ang);
  sinT[s * 64 + j] = sinf(ang);
}

// ---------------- RoPE apply (in-place, (b,h,s,d) bf16 layout) --------------
__global__ void rope_apply(u16* __restrict__ q, const float* __restrict__ cosT,
                           const float* __restrict__ sinT) {
  const int idx = blockIdx.x * 256 + threadIdx.x; // B*H*S*64 threads
  const int j = idx & 63;
  const int s = (idx >> 6) & (SEQ - 1);
  const int bh = idx >> 17;
  u16* base = q + ((long)bh * SEQ + s) * HD;
  float x1 = bf2f(base[j]), x2 = bf2f(base[j + 64]);
  float c = cosT[s * 64 + j], sn = sinT[s * 64 + j];
  base[j]      = f2bf(x1 * c - x2 * sn);
  base[j + 64] = f2bf(x1 * sn + x2 * c);
}

// ---------------- V transpose: (b,h,s,d) -> (b,h,d,s) bf16 ------------------
__global__ __launch_bounds__(256)
void transpose_v(const u16* __restrict__ in, u16* __restrict__ out) {
  __shared__ u16 T[64 * 72];
  const int tid = threadIdx.x;
  const int s0 = blockIdx.x * 64, d0 = blockIdx.y * 64, bh = blockIdx.z;
  const int r = tid >> 2, c = tid & 3;
  const u16* ip = in + ((long)bh * SEQ + s0 + r) * HD + d0 + c * 16;
  *(u16x8*)&T[r * 72 + c * 16]     = *(const u16x8*)ip;
  *(u16x8*)&T[r * 72 + c * 16 + 8] = *(const u16x8*)(ip + 8);
  __syncthreads();
  u16* op = out + ((long)bh * HD + d0 + r) * SEQ + s0 + c * 16;
  u16x8 a, b;
#pragma unroll
  for (int e = 0; e < 8; ++e) a[e] = T[(c * 16 + e) * 72 + r];
#pragma unroll
  for (int e = 0; e < 8; ++e) b[e] = T[(c * 16 + 8 + e) * 72 + r];
  *(u16x8*)op = a;
  *(u16x8*)(op + 8) = b;
}

// ---------------- GEMM: out = A(MxK) * Bw(NxK)^T + bias ---------------------
// MODE 0: write bf16 to (b,h,s,d) layout (QKV). MODE 1: write f32 row-major.
template <int MODE>
__global__ __launch_bounds__(256)
void gemm_bt(const u16* __restrict__ A, const u16* __restrict__ Bw,
             const float* __restrict__ bias, void* __restrict__ out,
             int M, int N, int K) {
  __shared__ u16 As[128 * 32];
  __shared__ u16 Bs[128 * 32];
  const int tid = threadIdx.x;
  const int wave = tid >> 6, lane = tid & 63;
  const int lr = lane & 15, lk = lane >> 4;
  const int m0 = blockIdx.y * 128, n0 = blockIdx.x * 128;
  const int wr = (wave >> 1) * 64, wc = (wave & 1) * 64;
  f32x4 acc[4][4] = {};
  for (int kt = 0; kt < K; kt += 32) {
#pragma unroll
    for (int c = 0; c < 2; ++c) {
      int idx = c * 256 + tid;            // 16B chunk id (512 per tile)
      int row = idx >> 2, col = (idx & 3) * 8;
      gload_lds16(A + (long)(m0 + row) * K + kt + col, As + idx * 8);
      gload_lds16(Bw + (long)(n0 + row) * K + kt + col, Bs + idx * 8);
    }
    __syncthreads();
    bf16x8 af[4], bfv[4];
#pragma unroll
    for (int m = 0; m < 4; ++m)
      af[m] = *(const bf16x8*)&As[(wr + m * 16 + lr) * 32 + lk * 8];
#pragma unroll
    for (int n = 0; n < 4; ++n)
      bfv[n] = *(const bf16x8*)&Bs[(wc + n * 16 + lr) * 32 + lk * 8];
#pragma unroll
    for (int m = 0; m < 4; ++m)
#pragma unroll
      for (int n = 0; n < 4; ++n)
        acc[m][n] = __builtin_amdgcn_mfma_f32_16x16x32_bf16(af[m], bfv[n], acc[m][n], 0, 0, 0);
    __syncthreads();
  }
  // Epilogue. C/D layout: row = lk*4 + i, col = lr  [m89-verified]
#pragma unroll
  for (int n = 0; n < 4; ++n) {
    const int col = n0 + wc + n * 16 + lr;
    const float bb = bias[col];
#pragma unroll
    for (int m = 0; m < 4; ++m) {
      const int rbase = m0 + wr + m * 16 + lk * 4;
#pragma unroll
      for (int i = 0; i < 4; ++i) {
        const int row = rbase + i;
        const float val = acc[m][n][i] + bb;
        if (MODE == 0) {
          const int b = row >> 11, s = row & (SEQ - 1);
          const int h = col >> 7, d = col & (HD - 1);
          ((u16*)out)[(((long)(b * NH + h)) * SEQ + s) * HD + d] = f2bf(val);
        } else {
          ((float*)out)[(long)row * EMB + col] = val;
        }
      }
    }
  }
}

// ---------------- Flash attention (causal) ----------------------------------
// Q,K in (b,h,s,d) bf16; Vt in (b,h,d,s) bf16. Block: 64 q-rows, 4 waves.
// Ks/Vts staged linearly via global_load_lds with PRE-SWIZZLED source
// (16B chunk ^= row&7); fragment reads apply the same XOR (rule #21).
__global__ __launch_bounds__(256)
void attn_fwd(const u16* __restrict__ Q, const u16* __restrict__ K,
              const u16* __restrict__ Vt, u16* __restrict__ O) {
  __shared__ u16 Ks[64 * 128];
  __shared__ u16 Vts[128 * 64];
  __shared__ u16 Ps[4][16 * 72];    // per-wave P tile, padded stride 72
  const int tid = threadIdx.x, wave = tid >> 6, lane = tid & 63;
  const int lr = lane & 15, lk = lane >> 4;
  const int bh = blockIdx.y;
  const int qt = gridDim.x - 1 - blockIdx.x;  // longest blocks first
  const int qs = qt * 64;
  const long hoff = (long)bh * SEQ * HD;      // same for (h,s,d) and (h,d,s)
  const u16* qb = Q + hoff + (long)(qs + wave * 16) * HD;

  bf16x8 qf[4];
#pragma unroll
  for (int ks = 0; ks < 4; ++ks)
    qf[ks] = *(const bf16x8*)(qb + (long)lr * HD + ks * 32 + lk * 8);

  f32x4 o[8] = {};
  float m_run[4] = {-1e30f, -1e30f, -1e30f, -1e30f};
  float l_run[4] = {0.f, 0.f, 0.f, 0.f};
  const float scale = 0.08838834764831845f;  // 1/sqrt(128)

  for (int t0 = 0; t0 <= qs; t0 += 64) {
    // stage K tile: LDS linear [64][128], source chunk pre-swizzled
#pragma unroll
    for (int c = 0; c < 4; ++c) {
      int i = c * 256 + tid;            // chunk id, 1024 total
      int row = i >> 4, cc = i & 15;
      int sc_ = cc ^ (row & 7);
      gload_lds16(K + hoff + (long)(t0 + row) * HD + sc_ * 8, Ks + i * 8);
    }
    // stage V^T tile: LDS linear [128][64], source chunk pre-swizzled
#pragma unroll
    for (int c = 0; c < 4; ++c) {
      int i = c * 256 + tid;            // chunk id, 1024 total
      int row = i >> 3, cc = i & 7;
      int sc_ = cc ^ (row & 7);
      gload_lds16(Vt + hoff + (long)row * SEQ + t0 + sc_ * 8, Vts + i * 8);
    }
    __syncthreads();

    // QK^T: scores 16x64 per wave (swizzled K-frag reads)
    f32x4 sc[4] = {};
#pragma unroll
    for (int tc = 0; tc < 4; ++tc) {
      const int rr = tc * 16 + lr;
#pragma unroll
      for (int ks = 0; ks < 4; ++ks) {
        bf16x8 kb = *(const bf16x8*)&Ks[rr * 128 + (((ks << 2) + lk) ^ (lr & 7)) * 8];
        sc[tc] = __builtin_amdgcn_mfma_f32_16x16x32_bf16(qf[ks], kb, sc[tc], 0, 0, 0);
      }
    }

    const bool diag = (t0 == qs);
    float rmax[4] = {-1e30f, -1e30f, -1e30f, -1e30f};
#pragma unroll
    for (int tc = 0; tc < 4; ++tc)
#pragma unroll
      for (int i = 0; i < 4; ++i) {
        float v = sc[tc][i] * scale;
        if (diag) {
          int tg = t0 + tc * 16 + lr;
          int qg = qs + wave * 16 + lk * 4 + i;
          if (tg > qg) v = -1e30f;
        }
        sc[tc][i] = v;
        rmax[i] = fmaxf(rmax[i], v);
      }
#pragma unroll
    for (int off = 1; off < 16; off <<= 1)
#pragma unroll
      for (int i = 0; i < 4; ++i)
        rmax[i] = fmaxf(rmax[i], __shfl_xor(rmax[i], off, 64));

    float alpha[4], rsum[4];
#pragma unroll
    for (int i = 0; i < 4; ++i) {
      float mn = fmaxf(m_run[i], rmax[i]);
      alpha[i] = __expf(m_run[i] - mn);
      m_run[i] = mn;
      rsum[i] = 0.f;
    }
#pragma unroll
    for (int tc = 0; tc < 4; ++tc)
#pragma unroll
      for (int i = 0; i < 4; ++i) {
        float p = __expf(sc[tc][i] - m_run[i]);
        sc[tc][i] = p;
        rsum[i] += p;
      }
#pragma unroll
    for (int off = 1; off < 16; off <<= 1)
#pragma unroll
      for (int i = 0; i < 4; ++i)
        rsum[i] += __shfl_xor(rsum[i], off, 64);
#pragma unroll
    for (int i = 0; i < 4; ++i) l_run[i] = l_run[i] * alpha[i] + rsum[i];
#pragma unroll
    for (int dc = 0; dc < 8; ++dc)
#pragma unroll
      for (int i = 0; i < 4; ++i) o[dc][i] *= alpha[i];

    // P (C-layout) -> LDS (stride 72) -> A-layout frags
    u16* pw = Ps[wave];
#pragma unroll
    for (int tc = 0; tc < 4; ++tc)
#pragma unroll
      for (int i = 0; i < 4; ++i)
        pw[(lk * 4 + i) * 72 + tc * 16 + lr] = f2bf(sc[tc][i]);
    asm volatile("s_waitcnt lgkmcnt(0)" ::: "memory");

    // PV: o(16x128) += P(16x64) * V(64x128)  (swizzled V^T-frag reads)
#pragma unroll
    for (int ks2 = 0; ks2 < 2; ++ks2) {
      bf16x8 pa = *(const bf16x8*)&pw[lr * 72 + ks2 * 32 + lk * 8];
#pragma unroll
      for (int dc = 0; dc < 8; ++dc) {
        const int dv = dc * 16 + lr;
        bf16x8 vb = *(const bf16x8*)&Vts[dv * 64 + (((ks2 << 2) + lk) ^ (lr & 7)) * 8];
        o[dc] = __builtin_amdgcn_mfma_f32_16x16x32_bf16(pa, vb, o[dc], 0, 0, 0);
      }
    }
    __syncthreads();
  }

  // epilogue: write (b,s,h*D+d) bf16
  const int b = bh >> 4, h = bh & 15;
#pragma unroll
  for (int i = 0; i < 4; ++i) {
    float inv = 1.0f / l_run[i];
    int s = qs + wave * 16 + lk * 4 + i;
    u16* orow = O + ((long)b * SEQ + s) * EMB + h * HD;
#pragma unroll
    for (int dc = 0; dc < 8; ++dc)
      orow[dc * 16 + lr] = f2bf(o[dc][i] * inv);
  }
}

// ---------------- launcher --------------------------------------------------
extern "C" void kernel_launch(void* const* d_in, const int* in_sizes, int n_in,
                              void* d_out, int out_size, void* d_ws, size_t ws_size,
                              hipStream_t stream) {
  const float* x  = (const float*)d_in[0];
  const float* wq = (const float*)d_in[1];
  const float* bq = (const float*)d_in[2];
  const float* wk = (const float*)d_in[3];
  const float* bk = (const float*)d_in[4];
  const float* wv = (const float*)d_in[5];
  const float* bv = (const float*)d_in[6];
  const float* wo = (const float*)d_in[7];
  const float* bo = (const float*)d_in[8];
  float* out = (float*)d_out;

  char* ws = (char*)d_ws;
  u16* xb  = (u16*)(ws + 0);            // 16,777,216 B (dead after QKV GEMMs)
  u16* wqb = (u16*)(ws + 16777216);     //  8,388,608 B
  u16* wkb = (u16*)(ws + 25165824);
  u16* wvb = (u16*)(ws + 33554432);
  u16* wob = (u16*)(ws + 41943040);
  u16* qr  = (u16*)(ws + 50331648);     // 16,777,216 B each
  u16* kr  = (u16*)(ws + 67108864);
  u16* vr  = (u16*)(ws + 83886080);
  u16* ao  = (u16*)(ws + 100663296);
  float* cosT = (float*)(ws + 117440512);
  float* sinT = (float*)(ws + 117964800);
  u16* vtr = xb;                        // reuse xb region for V^T (b,h,d,s)

  cvt_f32_bf16<<<2048, 256, 0, stream>>>(x, xb, BATCH * SEQ * EMB);
  cvt_f32_bf16<<<1024, 256, 0, stream>>>(wq, wqb, EMB * EMB);
  cvt_f32_bf16<<<1024, 256, 0, stream>>>(wk, wkb, EMB * EMB);
  cvt_f32_bf16<<<1024, 256, 0, stream>>>(wv, wvb, EMB * EMB);
  cvt_f32_bf16<<<1024, 256, 0, stream>>>(wo, wob, EMB * EMB);
  rope_table<<<SEQ, 64, 0, stream>>>(cosT, sinT);

  dim3 gg(EMB / 128, (BATCH * SEQ) / 128);
  gemm_bt<0><<<gg, 256, 0, stream>>>(xb, wqb, bq, qr, BATCH * SEQ, EMB, EMB);
  gemm_bt<0><<<gg, 256, 0, stream>>>(xb, wkb, bk, kr, BATCH * SEQ, EMB, EMB);
  gemm_bt<0><<<gg, 256, 0, stream>>>(xb, wvb, bv, vr, BATCH * SEQ, EMB, EMB);

  rope_apply<<<(BATCH * NH * SEQ * 64) / 256, 256, 0, stream>>>(qr, cosT, sinT);
  rope_apply<<<(BATCH * NH * SEQ * 64) / 256, 256, 0, stream>>>(kr, cosT, sinT);

  // V^T into the (now dead) xb region; then attention reads Q,K,V^T.
  transpose_v<<<dim3(SEQ / 64, HD / 64, BATCH * NH), 256, 0, stream>>>(vr, vtr);

  attn_fwd<<<dim3(SEQ / 64, BATCH * NH), 256, 0, stream>>>(qr, kr, vtr, ao);

  gemm_bt<1><<<gg, 256, 0, stream>>>(ao, wob, bo, out, BATCH * SEQ, EMB, EMB);
}